// Round 4
// baseline (164.236 us; speedup 1.0000x reference)
//
#include <hip/hip_runtime.h>

typedef __bf16 bf16;
typedef __attribute__((ext_vector_type(8))) __bf16 bf16x8;
typedef __attribute__((ext_vector_type(4))) __bf16 bf16x4;
typedef __attribute__((ext_vector_type(4))) float floatx4;

#define MFMA16(a, b, c) __builtin_amdgcn_mfma_f32_16x16x32_bf16((a), (b), (c), 0, 0, 0)

static constexpr int BB = 2, SS = 2048, DD = 1024, HH = 16;
static constexpr int MM = BB * SS;      // 4096
static constexpr int N_QKV = 3 * DD;    // 3072

__device__ __forceinline__ float exp2c(float x) {
#if __has_builtin(__builtin_amdgcn_exp2f)
    return __builtin_amdgcn_exp2f(x);
#else
    return exp2f(x);
#endif
}

// async 16B global->LDS (lane i of wave lands at ldsbase + i*16)
__device__ __forceinline__ void async16(const void* g, void* l) {
    __builtin_amdgcn_global_load_lds(
        (const __attribute__((address_space(1))) unsigned int*)g,
        (__attribute__((address_space(3))) unsigned int*)l, 16, 0, 0);
}

// ---------------- prep: x cast (blocks 0..4095) + W transpose (blocks 4096..8191) ----------------
__global__ __launch_bounds__(256) void prep_kernel(const float* __restrict__ x,
                                                   bf16* __restrict__ xb,
                                                   const float* __restrict__ w0,
                                                   const float* __restrict__ w1,
                                                   const float* __restrict__ w2,
                                                   const float* __restrict__ w3,
                                                   bf16* __restrict__ outT) {
    const int blk = blockIdx.x, tid = threadIdx.x;
    if (blk < 4096) {
        int i = blk * 1024 + tid * 4;
        float4 v = *(const float4*)(x + i);
        bf16x4 o;
        o[0] = (bf16)v.x; o[1] = (bf16)v.y; o[2] = (bf16)v.z; o[3] = (bf16)v.w;
        *(bf16x4*)(xb + i) = o;
    } else {
        __shared__ float tile[32][33];
        const int wblk = blk - 4096;
        const int z = wblk >> 10, rem = wblk & 1023;
        const int by = rem >> 5, bx = rem & 31;
        const float* src = (z == 0) ? w0 : (z == 1) ? w1 : (z == 2) ? w2 : w3;
        bf16* dst = outT + (size_t)z * DD * DD;
        const int y0 = by * 32, x0 = bx * 32;
        {
            const int tx = tid & 7, ty = tid >> 3;   // 8 x 32 threads, float4 each
            float4 v = *(const float4*)(src + (size_t)(y0 + ty) * DD + x0 + tx * 4);
            tile[ty][tx * 4 + 0] = v.x;
            tile[ty][tx * 4 + 1] = v.y;
            tile[ty][tx * 4 + 2] = v.z;
            tile[ty][tx * 4 + 3] = v.w;
        }
        __syncthreads();
        {
            const int tx = tid & 7, c = tid >> 3;    // output row x0+c, 4 cols per thread
            bf16x4 o;
            o[0] = (bf16)tile[tx * 4 + 0][c];
            o[1] = (bf16)tile[tx * 4 + 1][c];
            o[2] = (bf16)tile[tx * 4 + 2][c];
            o[3] = (bf16)tile[tx * 4 + 3][c];
            *(bf16x4*)(dst + (size_t)(x0 + c) * DD + y0 + tx * 4) = o;
        }
    }
}

// ---------------- 256x192 deep-pipelined GEMM (QKV projection) ----------------
// Verified r2 (correctness) + r3 (perf: ~24us, ~1075 TF at 100% fill).
// 8 waves (2m x 4n), per-wave C = 128x48 (8x3 fragments). LDS 112 KB.
// Per-wave FIFO: 7 loads/tile, order Ah0(2), B(3), Ah1(2).
//   phase0: vmcnt(2) [oldest 5 = Ah0+B done]; issue Ah0'+B' (5)
//   phase1: vmcnt(5) [oldest 2 = Ah1 done];   issue Ah1'   (2)
__global__ __launch_bounds__(512, 2) void gemm192_kernel(const bf16* __restrict__ A,
                                                         const bf16* __restrict__ Bt,
                                                         bf16* __restrict__ C,
                                                         bf16* __restrict__ Vt_g,
                                                         int K, int ldc) {
    __shared__ __align__(16) bf16 As[2 * 256 * 64];   // 64 KB
    __shared__ __align__(16) bf16 Bs[2 * 192 * 64];   // 48 KB
    const int tid = threadIdx.x, wave = tid >> 6, lane = tid & 63;
    const int quad = lane >> 4, l16 = lane & 15;
    const int wm = wave >> 2, wn = wave & 3;          // 2 x 4 wave grid
    const int m0 = blockIdx.y * 256, n0 = blockIdx.x * 192;
    const int l8r = lane >> 3, l8c = lane & 7;
    const int gch = (l8c ^ l8r) * 8;
    const int nk = K >> 6;

    floatx4 acc[2][4][3] = {};    // [mh][m'][n']
    bf16x8 af[4][2], bn[3][2];

#define VMW(N) asm volatile("s_waitcnt vmcnt(" #N ")" ::: "memory")
#define BARX __builtin_amdgcn_s_barrier()

#define STAGE_A(H, KN, BUF)                                                       \
    {                                                                             \
        _Pragma("unroll") for (int c = 0; c < 2; ++c) {                           \
            int r0 = (H) * 128 + c * 64 + wave * 8;                               \
            async16(A + (size_t)(m0 + r0 + l8r) * K + (KN) + gch,                 \
                    &As[(BUF) * 16384 + r0 * 64]);                                \
        }                                                                         \
    }
#define STAGE_B(KN, BUF)                                                          \
    {                                                                             \
        _Pragma("unroll") for (int c = 0; c < 3; ++c) {                           \
            int r0 = wave * 24 + c * 8;                                           \
            async16(Bt + (size_t)(n0 + r0 + l8r) * K + (KN) + gch,                \
                    &Bs[(BUF) * 12288 + r0 * 64]);                                \
        }                                                                         \
    }
#define READ_A(MH, BUF)                                                           \
    {                                                                             \
        _Pragma("unroll") for (int m = 0; m < 4; ++m) {                           \
            int row = (MH) * 128 + wm * 64 + m * 16 + l16;                        \
            _Pragma("unroll") for (int kk = 0; kk < 2; ++kk)                      \
                af[m][kk] = *(const bf16x8*)&As[(BUF) * 16384 + row * 64 +        \
                                               (((kk * 4 + quad) ^ (row & 7)) * 8)]; \
        }                                                                         \
    }
#define READ_B(BUF)                                                               \
    {                                                                             \
        _Pragma("unroll") for (int n = 0; n < 3; ++n) {                           \
            int row = wn * 48 + n * 16 + l16;                                     \
            _Pragma("unroll") for (int kk = 0; kk < 2; ++kk)                      \
                bn[n][kk] = *(const bf16x8*)&Bs[(BUF) * 12288 + row * 64 +        \
                                               (((kk * 4 + quad) ^ (row & 7)) * 8)]; \
        }                                                                         \
    }
#define MMAC(MH)                                                                  \
    {                                                                             \
        __builtin_amdgcn_s_setprio(1);                                            \
        _Pragma("unroll") for (int m = 0; m < 4; ++m)                             \
            _Pragma("unroll") for (int n = 0; n < 3; ++n)                         \
                _Pragma("unroll") for (int kk = 0; kk < 2; ++kk)                  \
                    acc[MH][m][n] = MFMA16(af[m][kk], bn[n][kk], acc[MH][m][n]);  \
        __builtin_amdgcn_s_setprio(0);                                            \
    }

    // prologue: tile 0 into buf 0, FIFO order Ah0, B, Ah1 (7 loads/wave)
    STAGE_A(0, 0, 0);
    STAGE_B(0, 0);
    STAGE_A(1, 0, 0);

    for (int kt = 0; kt < nk; ++kt) {
        const int buf = kt & 1;
        const int knext = (kt + 1) << 6;
        const bool last = (kt == nk - 1);

        // phase 0 (mh=0): needs Ah0 + B of current tile (oldest 5 of 7)
        VMW(2);
        BARX;
        READ_A(0, buf);
        READ_B(buf);
        if (!last) { STAGE_A(0, knext, buf ^ 1); STAGE_B(knext, buf ^ 1); }
        MMAC(0);

        // phase 1 (mh=1): needs Ah1 of current tile (oldest 2)
        if (!last) { VMW(5); } else { VMW(0); }
        BARX;
        READ_A(1, buf);
        if (!last) STAGE_A(1, knext, buf ^ 1);
        MMAC(1);
    }

#undef STAGE_A
#undef STAGE_B
#undef READ_A
#undef READ_B
#undef MMAC

    // epilogue: per-fragment routing across the QK|V boundary (col 2048, 16-aligned)
#pragma unroll
    for (int mh = 0; mh < 2; ++mh)
#pragma unroll
        for (int m = 0; m < 4; ++m)
#pragma unroll
            for (int n = 0; n < 3; ++n) {
                int grow = m0 + mh * 128 + wm * 64 + m * 16 + quad * 4;
                int gcol0 = n0 + wn * 48 + n * 16;
                if (gcol0 >= 2048) {
                    int bb = grow >> 11, s = grow & (SS - 1);
                    int vcol = gcol0 + l16 - 2048;
                    int hh = vcol >> 6, hd = vcol & 63;
                    bf16x4 pk;
#pragma unroll
                    for (int r = 0; r < 4; ++r) pk[r] = (bf16)acc[mh][m][n][r];
                    *(bf16x4*)&Vt_g[(((size_t)(bb * 16 + hh)) * 64 + hd) * SS + s] = pk;
                } else {
#pragma unroll
                    for (int r = 0; r < 4; ++r)
                        C[(size_t)(grow + r) * ldc + gcol0 + l16] = (bf16)acc[mh][m][n][r];
                }
            }
}

// ---------------- 128x128 deep-pipelined GEMM (output projection, fp32 + bias) ----------------
// Parameter-adaptation of the r3-verified 2-phase counted-vmcnt schedule.
// Grid 8x32 = 256 blocks = 1/CU (100% fill; old 128x64 m97 kernel was the last
// non-pipelined GEMM at ~600 TF). 8 waves (2m x 4n), per-wave C = 64x32
// (rows split as 2x32: one 32-row chunk in each A-half -> both phases busy).
// Per-wave FIFO: 4 loads/tile, order Ah0(1), B(2), Ah1(1).
//   phase0: vmcnt(1) [oldest 3 = Ah0+B done]; issue Ah0'+B' (3)
//   phase1: vmcnt(3) [oldest 1 = Ah1 done];   issue Ah1'   (1)
//   invariant: 4 outstanding at each phase0 entry; last tile 1 -> 0.
// Accumulation per output element: kt asc, kk asc; bias added once at end ->
// bit-identical to the previous out-projection kernel.
__global__ __launch_bounds__(512, 2) void gemmo_kernel(const bf16* __restrict__ A,
                                                       const bf16* __restrict__ Bt,
                                                       float* __restrict__ C,
                                                       const float* __restrict__ bias,
                                                       int K, int ldc) {
    __shared__ __align__(16) bf16 As[2 * 128 * 64];   // 32 KB
    __shared__ __align__(16) bf16 Bs[2 * 128 * 64];   // 32 KB
    const int tid = threadIdx.x, wave = tid >> 6, lane = tid & 63;
    const int quad = lane >> 4, l16 = lane & 15;
    const int wm = wave >> 2, wn = wave & 3;          // 2 x 4 wave grid
    const int m0 = blockIdx.y * 128, n0 = blockIdx.x * 128;
    const int l8r = lane >> 3, l8c = lane & 7;
    const int gch = (l8c ^ l8r) * 8;
    const int nk = K >> 6;

    floatx4 acc[2][2][2] = {};    // [mh][m'][n']
    bf16x8 af[2][2], bn[2][2];

#define STAGE_A(H, KN, BUF)                                                       \
    {                                                                             \
        int r0 = (H) * 64 + wave * 8;                                             \
        async16(A + (size_t)(m0 + r0 + l8r) * K + (KN) + gch,                     \
                &As[(BUF) * 8192 + r0 * 64]);                                     \
    }
#define STAGE_B(KN, BUF)                                                          \
    {                                                                             \
        _Pragma("unroll") for (int c = 0; c < 2; ++c) {                           \
            int r0 = wave * 16 + c * 8;                                           \
            async16(Bt + (size_t)(n0 + r0 + l8r) * K + (KN) + gch,                \
                    &Bs[(BUF) * 8192 + r0 * 64]);                                 \
        }                                                                         \
    }
#define READ_A(MH, BUF)                                                           \
    {                                                                             \
        _Pragma("unroll") for (int m = 0; m < 2; ++m) {                           \
            int row = (MH) * 64 + wm * 32 + m * 16 + l16;                         \
            _Pragma("unroll") for (int kk = 0; kk < 2; ++kk)                      \
                af[m][kk] = *(const bf16x8*)&As[(BUF) * 8192 + row * 64 +         \
                                               (((kk * 4 + quad) ^ (row & 7)) * 8)]; \
        }                                                                         \
    }
#define READ_B(BUF)                                                               \
    {                                                                             \
        _Pragma("unroll") for (int n = 0; n < 2; ++n) {                           \
            int row = wn * 32 + n * 16 + l16;                                     \
            _Pragma("unroll") for (int kk = 0; kk < 2; ++kk)                      \
                bn[n][kk] = *(const bf16x8*)&Bs[(BUF) * 8192 + row * 64 +         \
                                               (((kk * 4 + quad) ^ (row & 7)) * 8)]; \
        }                                                                         \
    }
#define MMAC(MH)                                                                  \
    {                                                                             \
        __builtin_amdgcn_s_setprio(1);                                            \
        _Pragma("unroll") for (int m = 0; m < 2; ++m)                             \
            _Pragma("unroll") for (int n = 0; n < 2; ++n)                         \
                _Pragma("unroll") for (int kk = 0; kk < 2; ++kk)                  \
                    acc[MH][m][n] = MFMA16(af[m][kk], bn[n][kk], acc[MH][m][n]);  \
        __builtin_amdgcn_s_setprio(0);                                            \
    }

    // prologue: tile 0 into buf 0, FIFO order Ah0, B, Ah1 (4 loads/wave)
    STAGE_A(0, 0, 0);
    STAGE_B(0, 0);
    STAGE_A(1, 0, 0);

    for (int kt = 0; kt < nk; ++kt) {
        const int buf = kt & 1;
        const int knext = (kt + 1) << 6;
        const bool last = (kt == nk - 1);

        // phase 0 (mh=0): needs Ah0 + B of current tile (oldest 3 of 4)
        VMW(1);
        BARX;
        READ_A(0, buf);
        READ_B(buf);
        if (!last) { STAGE_A(0, knext, buf ^ 1); STAGE_B(knext, buf ^ 1); }
        MMAC(0);

        // phase 1 (mh=1): needs Ah1 of current tile (oldest 1)
        if (!last) { VMW(3); } else { VMW(0); }
        BARX;
        READ_A(1, buf);
        if (!last) STAGE_A(1, knext, buf ^ 1);
        MMAC(1);
    }

#undef VMW
#undef BARX
#undef STAGE_A
#undef STAGE_B
#undef READ_A
#undef READ_B
#undef MMAC

#pragma unroll
    for (int mh = 0; mh < 2; ++mh)
#pragma unroll
        for (int m = 0; m < 2; ++m)
#pragma unroll
            for (int n = 0; n < 2; ++n)
#pragma unroll
                for (int r = 0; r < 4; ++r) {
                    int row = m0 + mh * 64 + wm * 32 + m * 16 + quad * 4 + r;
                    int col = n0 + wn * 32 + n * 16 + l16;
                    C[(size_t)row * ldc + col] = acc[mh][m][n][r] + bias[col];
                }
}

// ---------------- fused causal attention (round-1 version, unchanged) ----------------
__global__ __launch_bounds__(256, 4) void attn_kernel(const bf16* __restrict__ QKV,
                                                      const bf16* __restrict__ Vt_g,
                                                      bf16* __restrict__ ctx) {
    __shared__ __align__(16) bf16 smem[20480];   // 40 KB
    bf16* Ks = smem;           // [2][64][64]
    bf16* Vt = smem + 8192;    // [2][64][64]  [hd][key]
    bf16* Ps = smem + 16384;   // [wave][16][64]; also Q staging (wave-local rows)
    bf16* Qs = Ps;

    const int tid = threadIdx.x, wave = tid >> 6, lane = tid & 63;
    const int quad = lane >> 4, l16 = lane & 15;
    const int gb = blockIdx.x;
    const int xcd = gb & 7, rr = gb >> 3;
    const int hi = rr >> 5, lo = rr & 31;
    const int t = (hi == 0) ? lo : (hi == 1) ? (31 - lo)
                : (hi == 2) ? (lo ^ 16) : (31 - (lo ^ 16));
    const int bh = xcd * 4 + hi;
    const int b = bh >> 4, h = bh & 15;
    const int q0 = t * 64;
    const size_t base = (size_t)(b * SS) * N_QKV;
    const bf16* Vg = Vt_g + (size_t)bh * 64 * SS;
    constexpr float C2 = 0.18033688011112042f;   // 0.125 * log2(e)
    const int l8r = lane >> 3, l8c = lane & 7;
    const int gch = (l8c ^ l8r) * 8;
    const int swz = l16 & 7;
    const int nkt = t + 1;

    {   // stage Q [64][64] swizzled into Ps region (wave-local 16 rows)
#pragma unroll
        for (int c = 0; c < 2; ++c) {
            int r0 = wave * 16 + c * 8;
            async16(QKV + base + (size_t)(q0 + r0 + l8r) * N_QKV + h * 64 + gch,
                    Qs + r0 * 64);
            // K/V tile 0 into buf 0
            async16(QKV + base + (size_t)(r0 + l8r) * N_QKV + DD + h * 64 + gch,
                    Ks + r0 * 64);
            async16(Vg + (size_t)(r0 + l8r) * SS + gch, Vt + r0 * 64);
        }
    }
    __syncthreads();   // vmcnt drained: Q + tile0 staged

    bf16x8 qf[2];
#pragma unroll
    for (int cc = 0; cc < 2; ++cc) {
        int row = wave * 16 + l16;
        qf[cc] = *(const bf16x8*)&Qs[row * 64 + ((cc * 4 + quad) ^ swz) * 8];
    }

    bf16x8 onesf = {};
    if (l16 == 0) {
#pragma unroll
        for (int e = 0; e < 8; ++e) onesf[e] = (bf16)1.0f;
    }

    floatx4 accv[4] = {};
    floatx4 acc5 = {};
    const int qg = q0 + wave * 16 + l16;

    for (int kt = 0; kt < nkt; ++kt) {
        const int buf = kt & 1;
        if (kt + 1 < nkt) {   // DMA next tile into buf^1; completes by end barrier
            const int k0n = (kt + 1) * 64;
            const int dst = (buf ^ 1) * 4096;
#pragma unroll
            for (int c = 0; c < 2; ++c) {
                int r0 = wave * 16 + c * 8;
                async16(QKV + base + (size_t)(k0n + r0 + l8r) * N_QKV + DD + h * 64 + gch,
                        Ks + dst + r0 * 64);
                async16(Vg + (size_t)(r0 + l8r) * SS + k0n + gch, Vt + dst + r0 * 64);
            }
        }
        const int k0 = kt * 64;

        // S^T tile: rows = keys, cols = q (l16)
        floatx4 st[4];
#pragma unroll
        for (int j = 0; j < 4; ++j) st[j] = (floatx4){};
        __builtin_amdgcn_s_setprio(1);
#pragma unroll
        for (int cc = 0; cc < 2; ++cc)
#pragma unroll
            for (int j = 0; j < 4; ++j) {
                bf16x8 kf = *(const bf16x8*)&Ks[buf * 4096 + (j * 16 + l16) * 64
                                                + ((cc * 4 + quad) ^ swz) * 8];
                st[j] = MFMA16(kf, qf[cc], st[j]);
            }
        __builtin_amdgcn_s_setprio(0);

        // causal mask: only the diagonal tile (kt == t)
        if (kt == nkt - 1) {
#pragma unroll
            for (int j = 0; j < 4; ++j) {
                int kb = k0 + j * 16 + quad * 4;
#pragma unroll
                for (int r = 0; r < 4; ++r)
                    if (kb + r > qg) st[j][r] = -__builtin_inff();
            }
        }

        // P = exp2(s*C2)  (fixed-max: no running max / rescale)
#pragma unroll
        for (int j = 0; j < 4; ++j) {
            bf16x4 pk4;
#pragma unroll
            for (int r = 0; r < 4; ++r)
                pk4[r] = (bf16)exp2c(st[j][r] * C2);
            *(bf16x4*)&Ps[wave * 1024 + l16 * 64
                          + ((2 * j + (quad >> 1)) ^ swz) * 8 + (quad & 1) * 4] = pk4;
        }

        // PV + denominator
        bf16x8 pf[2];
#pragma unroll
        for (int cc = 0; cc < 2; ++cc)
            pf[cc] = *(const bf16x8*)&Ps[wave * 1024 + l16 * 64
                                         + ((cc * 4 + quad) ^ swz) * 8];
        __builtin_amdgcn_s_setprio(1);
#pragma unroll
        for (int cc = 0; cc < 2; ++cc)
#pragma unroll
            for (int j = 0; j < 4; ++j) {
                bf16x8 vt = *(const bf16x8*)&Vt[buf * 4096 + (j * 16 + l16) * 64
                                                + ((cc * 4 + quad) ^ swz) * 8];
                accv[j] = MFMA16(pf[cc], vt, accv[j]);
            }
        acc5 = MFMA16(pf[0], onesf, acc5);
        acc5 = MFMA16(pf[1], onesf, acc5);
        __builtin_amdgcn_s_setprio(0);

        __syncthreads();   // readers done + next-tile DMA drained
    }

    // epilogue: denominators in acc5 col 0 (lanes l16==0)
    float inv[4];
#pragma unroll
    for (int r = 0; r < 4; ++r)
        inv[r] = 1.0f / __shfl(acc5[r], lane & 48, 64);
#pragma unroll
    for (int j = 0; j < 4; ++j)
#pragma unroll
        for (int r = 0; r < 4; ++r) {
            int row = b * SS + q0 + wave * 16 + quad * 4 + r;
            int col = h * 64 + j * 16 + l16;
            ctx[(size_t)row * DD + col] = (bf16)(accv[j][r] * inv[r]);
        }
}

extern "C" void kernel_launch(void* const* d_in, const int* in_sizes, int n_in,
                              void* d_out, int out_size, void* d_ws, size_t ws_size,
                              hipStream_t stream) {
    const float* x  = (const float*)d_in[0];
    const float* Wq = (const float*)d_in[1];
    const float* Wk = (const float*)d_in[2];
    const float* Wv = (const float*)d_in[3];
    const float* Wo = (const float*)d_in[4];
    const float* bo = (const float*)d_in[5];
    float* out = (float*)d_out;

    char* ws = (char*)d_ws;
    bf16* xb   = (bf16*)ws;                         //  8 MB
    bf16* WT   = (bf16*)(ws + (size_t)(8  << 20));  //  8 MB
    bf16* QKV  = (bf16*)(ws + (size_t)(16 << 20));  // 24 MB (V third unused)
    bf16* ctxb = (bf16*)(ws + (size_t)(40 << 20));  //  8 MB
    bf16* Vt_g = (bf16*)(ws + (size_t)(48 << 20));  //  8 MB

    prep_kernel<<<dim3(8192), dim3(256), 0, stream>>>(x, xb, Wq, Wk, Wv, Wo, WT);
    gemm192_kernel<<<dim3(N_QKV / 192, MM / 256), dim3(512), 0, stream>>>(
        xb, WT, QKV, Vt_g, DD, N_QKV);
    attn_kernel<<<dim3(1024), dim3(256), 0, stream>>>(QKV, Vt_g, ctxb);
    gemmo_kernel<<<dim3(DD / 128, MM / 128), dim3(512), 0, stream>>>(
        ctxb, WT + (size_t)3 * DD * DD, out, bo, DD, DD);
}

// Round 5
// 162.408 us; speedup vs baseline: 1.0113x; 1.0113x over previous
//
#include <hip/hip_runtime.h>

typedef __bf16 bf16;
typedef __attribute__((ext_vector_type(8))) __bf16 bf16x8;
typedef __attribute__((ext_vector_type(4))) __bf16 bf16x4;
typedef __attribute__((ext_vector_type(4))) float floatx4;

#define MFMA16(a, b, c) __builtin_amdgcn_mfma_f32_16x16x32_bf16((a), (b), (c), 0, 0, 0)

static constexpr int BB = 2, SS = 2048, DD = 1024, HH = 16;
static constexpr int MM = BB * SS;      // 4096
static constexpr int N_QKV = 3 * DD;    // 3072

__device__ __forceinline__ float exp2c(float x) {
#if __has_builtin(__builtin_amdgcn_exp2f)
    return __builtin_amdgcn_exp2f(x);
#else
    return exp2f(x);
#endif
}

// async 16B global->LDS (lane i of wave lands at ldsbase + i*16)
__device__ __forceinline__ void async16(const void* g, void* l) {
    __builtin_amdgcn_global_load_lds(
        (const __attribute__((address_space(1))) unsigned int*)g,
        (__attribute__((address_space(3))) unsigned int*)l, 16, 0, 0);
}

// ---------------- prep: x cast (blocks 0..4095) + W transpose (blocks 4096..8191) ----------------
__global__ __launch_bounds__(256) void prep_kernel(const float* __restrict__ x,
                                                   bf16* __restrict__ xb,
                                                   const float* __restrict__ w0,
                                                   const float* __restrict__ w1,
                                                   const float* __restrict__ w2,
                                                   const float* __restrict__ w3,
                                                   bf16* __restrict__ outT) {
    const int blk = blockIdx.x, tid = threadIdx.x;
    if (blk < 4096) {
        int i = blk * 1024 + tid * 4;
        float4 v = *(const float4*)(x + i);
        bf16x4 o;
        o[0] = (bf16)v.x; o[1] = (bf16)v.y; o[2] = (bf16)v.z; o[3] = (bf16)v.w;
        *(bf16x4*)(xb + i) = o;
    } else {
        __shared__ float tile[32][33];
        const int wblk = blk - 4096;
        const int z = wblk >> 10, rem = wblk & 1023;
        const int by = rem >> 5, bx = rem & 31;
        const float* src = (z == 0) ? w0 : (z == 1) ? w1 : (z == 2) ? w2 : w3;
        bf16* dst = outT + (size_t)z * DD * DD;
        const int y0 = by * 32, x0 = bx * 32;
        {
            const int tx = tid & 7, ty = tid >> 3;   // 8 x 32 threads, float4 each
            float4 v = *(const float4*)(src + (size_t)(y0 + ty) * DD + x0 + tx * 4);
            tile[ty][tx * 4 + 0] = v.x;
            tile[ty][tx * 4 + 1] = v.y;
            tile[ty][tx * 4 + 2] = v.z;
            tile[ty][tx * 4 + 3] = v.w;
        }
        __syncthreads();
        {
            const int tx = tid & 7, c = tid >> 3;    // output row x0+c, 4 cols per thread
            bf16x4 o;
            o[0] = (bf16)tile[tx * 4 + 0][c];
            o[1] = (bf16)tile[tx * 4 + 1][c];
            o[2] = (bf16)tile[tx * 4 + 2][c];
            o[3] = (bf16)tile[tx * 4 + 3][c];
            *(bf16x4*)(dst + (size_t)(x0 + c) * DD + y0 + tx * 4) = o;
        }
    }
}

#define VMW(N) asm volatile("s_waitcnt vmcnt(" #N ")" ::: "memory")
#define BARX __builtin_amdgcn_s_barrier()

// ---------------- 256x192 deep-pipelined GEMM (QKV projection) ----------------
// r3-verified structure, prefetch deepened 2->3 phases (r4 post-mortem: phase-entry
// vmcnt was waiting on loads issued only ~2 short phases (~400cyc) earlier vs
// 200-900cyc L2/L3/HBM latency). Stage issue points moved one phase earlier; no new
// barriers needed because staged regions are disjoint from concurrently-read regions:
//   p0(t): reads A0+B of buf; stages A1(t+1) -> buf^1 rows 128-255 (last read
//          p1(t-1); those ds_reads complete before any wave passes p0's entry
//          barrier, since lgkm drains before the MFMAs that precede the barrier).
//   p1(t): reads A1 (rows 128-255) of buf; stages A0+B(t+2) -> buf rows 0-127 /
//          Bs[buf] (last read p0(t); separated by p1's entry barrier).
// Per-wave FIFO (7 loads/tile: A0=2,B=3,A1=2), simulated:
//   prologue: A0_0,B_0,A1_0,A0_1,B_1 = 12 outstanding.
//   p0: vmcnt(7) drains A0_t+B_t (5); issue A1_{t+1} (2).
//   p1: vmcnt(7) drains A1_t (2);    issue A0_{t+2}+B_{t+2} (5).
//   last tile: p0 vmcnt(2), p1 vmcnt(0). Never drains to 0 mid-loop.
__global__ __launch_bounds__(512, 2) void gemm192_kernel(const bf16* __restrict__ A,
                                                         const bf16* __restrict__ Bt,
                                                         bf16* __restrict__ C,
                                                         bf16* __restrict__ Vt_g,
                                                         int K, int ldc) {
    __shared__ __align__(16) bf16 As[2 * 256 * 64];   // 64 KB
    __shared__ __align__(16) bf16 Bs[2 * 192 * 64];   // 48 KB
    const int tid = threadIdx.x, wave = tid >> 6, lane = tid & 63;
    const int quad = lane >> 4, l16 = lane & 15;
    const int wm = wave >> 2, wn = wave & 3;          // 2 x 4 wave grid
    const int m0 = blockIdx.y * 256, n0 = blockIdx.x * 192;
    const int l8r = lane >> 3, l8c = lane & 7;
    const int gch = (l8c ^ l8r) * 8;
    const int nk = K >> 6;

    floatx4 acc[2][4][3] = {};    // [mh][m'][n']
    bf16x8 af[4][2], bn[3][2];

#define STAGE_A(H, KN, BUF)                                                       \
    {                                                                             \
        _Pragma("unroll") for (int c = 0; c < 2; ++c) {                           \
            int r0 = (H) * 128 + c * 64 + wave * 8;                               \
            async16(A + (size_t)(m0 + r0 + l8r) * K + (KN) + gch,                 \
                    &As[(BUF) * 16384 + r0 * 64]);                                \
        }                                                                         \
    }
#define STAGE_B(KN, BUF)                                                          \
    {                                                                             \
        _Pragma("unroll") for (int c = 0; c < 3; ++c) {                           \
            int r0 = wave * 24 + c * 8;                                           \
            async16(Bt + (size_t)(n0 + r0 + l8r) * K + (KN) + gch,                \
                    &Bs[(BUF) * 12288 + r0 * 64]);                                \
        }                                                                         \
    }
#define READ_A(MH, BUF)                                                           \
    {                                                                             \
        _Pragma("unroll") for (int m = 0; m < 4; ++m) {                           \
            int row = (MH) * 128 + wm * 64 + m * 16 + l16;                        \
            _Pragma("unroll") for (int kk = 0; kk < 2; ++kk)                      \
                af[m][kk] = *(const bf16x8*)&As[(BUF) * 16384 + row * 64 +        \
                                               (((kk * 4 + quad) ^ (row & 7)) * 8)]; \
        }                                                                         \
    }
#define READ_B(BUF)                                                               \
    {                                                                             \
        _Pragma("unroll") for (int n = 0; n < 3; ++n) {                           \
            int row = wn * 48 + n * 16 + l16;                                     \
            _Pragma("unroll") for (int kk = 0; kk < 2; ++kk)                      \
                bn[n][kk] = *(const bf16x8*)&Bs[(BUF) * 12288 + row * 64 +        \
                                               (((kk * 4 + quad) ^ (row & 7)) * 8)]; \
        }                                                                         \
    }
#define MMAC(MH)                                                                  \
    {                                                                             \
        __builtin_amdgcn_s_setprio(1);                                            \
        _Pragma("unroll") for (int m = 0; m < 4; ++m)                             \
            _Pragma("unroll") for (int n = 0; n < 3; ++n)                         \
                _Pragma("unroll") for (int kk = 0; kk < 2; ++kk)                  \
                    acc[MH][m][n] = MFMA16(af[m][kk], bn[n][kk], acc[MH][m][n]);  \
        __builtin_amdgcn_s_setprio(0);                                            \
    }

    // prologue (FIFO): A0_0, B_0, A1_0, A0_1, B_1  -> 12 outstanding
    STAGE_A(0, 0, 0);
    STAGE_B(0, 0);
    STAGE_A(1, 0, 0);
    STAGE_A(0, 64, 1);
    STAGE_B(64, 1);

    for (int kt = 0; kt < nk; ++kt) {
        const int buf = kt & 1;
        const int k1 = (kt + 1) << 6, k2 = (kt + 2) << 6;
        const bool last = (kt == nk - 1);

        // phase 0 (mh=0): needs A0+B of tile kt (issued 3 phases ago)
        if (!last) { VMW(7); } else { VMW(2); }
        BARX;
        READ_A(0, buf);
        READ_B(buf);
        if (kt + 1 < nk) STAGE_A(1, k1, buf ^ 1);   // rows 128-255 of buf^1
        MMAC(0);

        // phase 1 (mh=1): needs A1 of tile kt
        if (!last) { VMW(7); } else { VMW(0); }
        BARX;
        READ_A(1, buf);
        if (kt + 2 < nk) { STAGE_A(0, k2, buf); STAGE_B(k2, buf); }  // rows 0-127 of buf
        MMAC(1);
    }

#undef STAGE_A
#undef STAGE_B
#undef READ_A
#undef READ_B
#undef MMAC

    // epilogue: per-fragment routing across the QK|V boundary (col 2048, 16-aligned)
#pragma unroll
    for (int mh = 0; mh < 2; ++mh)
#pragma unroll
        for (int m = 0; m < 4; ++m)
#pragma unroll
            for (int n = 0; n < 3; ++n) {
                int grow = m0 + mh * 128 + wm * 64 + m * 16 + quad * 4;
                int gcol0 = n0 + wn * 48 + n * 16;
                if (gcol0 >= 2048) {
                    int bb = grow >> 11, s = grow & (SS - 1);
                    int vcol = gcol0 + l16 - 2048;
                    int hh = vcol >> 6, hd = vcol & 63;
                    bf16x4 pk;
#pragma unroll
                    for (int r = 0; r < 4; ++r) pk[r] = (bf16)acc[mh][m][n][r];
                    *(bf16x4*)&Vt_g[(((size_t)(bb * 16 + hh)) * 64 + hd) * SS + s] = pk;
                } else {
#pragma unroll
                    for (int r = 0; r < 4; ++r)
                        C[(size_t)(grow + r) * ldc + gcol0 + l16] = (bf16)acc[mh][m][n][r];
                }
            }
}

// ---------------- 128x128 deep-pipelined GEMM (output projection, fp32 + bias) ----------------
// Same 3-phase-deep prefetch as gemm192 (same disjointness argument: A0 = rows 0-63,
// A1 = rows 64-127). Per-wave FIFO (4 loads/tile: A0=1,B=2,A1=1), simulated:
//   prologue 7 outstanding; p0: vmcnt(4) drains A0_t+B_t (3), issue A1_{t+1} (1);
//   p1: vmcnt(4) drains A1_t (1), issue A0_{t+2}+B_{t+2} (3).
//   last tile: p0 vmcnt(1), p1 vmcnt(0).
__global__ __launch_bounds__(512, 2) void gemmo_kernel(const bf16* __restrict__ A,
                                                       const bf16* __restrict__ Bt,
                                                       float* __restrict__ C,
                                                       const float* __restrict__ bias,
                                                       int K, int ldc) {
    __shared__ __align__(16) bf16 As[2 * 128 * 64];   // 32 KB
    __shared__ __align__(16) bf16 Bs[2 * 128 * 64];   // 32 KB
    const int tid = threadIdx.x, wave = tid >> 6, lane = tid & 63;
    const int quad = lane >> 4, l16 = lane & 15;
    const int wm = wave >> 2, wn = wave & 3;          // 2 x 4 wave grid
    const int m0 = blockIdx.y * 128, n0 = blockIdx.x * 128;
    const int l8r = lane >> 3, l8c = lane & 7;
    const int gch = (l8c ^ l8r) * 8;
    const int nk = K >> 6;

    floatx4 acc[2][2][2] = {};    // [mh][m'][n']
    bf16x8 af[2][2], bn[2][2];

#define STAGE_A(H, KN, BUF)                                                       \
    {                                                                             \
        int r0 = (H) * 64 + wave * 8;                                             \
        async16(A + (size_t)(m0 + r0 + l8r) * K + (KN) + gch,                     \
                &As[(BUF) * 8192 + r0 * 64]);                                     \
    }
#define STAGE_B(KN, BUF)                                                          \
    {                                                                             \
        _Pragma("unroll") for (int c = 0; c < 2; ++c) {                           \
            int r0 = wave * 16 + c * 8;                                           \
            async16(Bt + (size_t)(n0 + r0 + l8r) * K + (KN) + gch,                \
                    &Bs[(BUF) * 8192 + r0 * 64]);                                 \
        }                                                                         \
    }
#define READ_A(MH, BUF)                                                           \
    {                                                                             \
        _Pragma("unroll") for (int m = 0; m < 2; ++m) {                           \
            int row = (MH) * 64 + wm * 32 + m * 16 + l16;                         \
            _Pragma("unroll") for (int kk = 0; kk < 2; ++kk)                      \
                af[m][kk] = *(const bf16x8*)&As[(BUF) * 8192 + row * 64 +         \
                                               (((kk * 4 + quad) ^ (row & 7)) * 8)]; \
        }                                                                         \
    }
#define READ_B(BUF)                                                               \
    {                                                                             \
        _Pragma("unroll") for (int n = 0; n < 2; ++n) {                           \
            int row = wn * 32 + n * 16 + l16;                                     \
            _Pragma("unroll") for (int kk = 0; kk < 2; ++kk)                      \
                bn[n][kk] = *(const bf16x8*)&Bs[(BUF) * 8192 + row * 64 +         \
                                               (((kk * 4 + quad) ^ (row & 7)) * 8)]; \
        }                                                                         \
    }
#define MMAC(MH)                                                                  \
    {                                                                             \
        __builtin_amdgcn_s_setprio(1);                                            \
        _Pragma("unroll") for (int m = 0; m < 2; ++m)                             \
            _Pragma("unroll") for (int n = 0; n < 2; ++n)                         \
                _Pragma("unroll") for (int kk = 0; kk < 2; ++kk)                  \
                    acc[MH][m][n] = MFMA16(af[m][kk], bn[n][kk], acc[MH][m][n]);  \
        __builtin_amdgcn_s_setprio(0);                                            \
    }

    // prologue (FIFO): A0_0, B_0, A1_0, A0_1, B_1 -> 7 outstanding
    STAGE_A(0, 0, 0);
    STAGE_B(0, 0);
    STAGE_A(1, 0, 0);
    STAGE_A(0, 64, 1);
    STAGE_B(64, 1);

    for (int kt = 0; kt < nk; ++kt) {
        const int buf = kt & 1;
        const int k1 = (kt + 1) << 6, k2 = (kt + 2) << 6;
        const bool last = (kt == nk - 1);

        // phase 0 (mh=0): needs A0+B of tile kt
        if (!last) { VMW(4); } else { VMW(1); }
        BARX;
        READ_A(0, buf);
        READ_B(buf);
        if (kt + 1 < nk) STAGE_A(1, k1, buf ^ 1);
        MMAC(0);

        // phase 1 (mh=1): needs A1 of tile kt
        if (!last) { VMW(4); } else { VMW(0); }
        BARX;
        READ_A(1, buf);
        if (kt + 2 < nk) { STAGE_A(0, k2, buf); STAGE_B(k2, buf); }
        MMAC(1);
    }

#undef VMW
#undef BARX
#undef STAGE_A
#undef STAGE_B
#undef READ_A
#undef READ_B
#undef MMAC

#pragma unroll
    for (int mh = 0; mh < 2; ++mh)
#pragma unroll
        for (int m = 0; m < 2; ++m)
#pragma unroll
            for (int n = 0; n < 2; ++n)
#pragma unroll
                for (int r = 0; r < 4; ++r) {
                    int row = m0 + mh * 64 + wm * 32 + m * 16 + quad * 4 + r;
                    int col = n0 + wn * 32 + n * 16 + l16;
                    C[(size_t)row * ldc + col] = acc[mh][m][n][r] + bias[col];
                }
}

// ---------------- fused causal attention (round-1 version, unchanged) ----------------
__global__ __launch_bounds__(256, 4) void attn_kernel(const bf16* __restrict__ QKV,
                                                      const bf16* __restrict__ Vt_g,
                                                      bf16* __restrict__ ctx) {
    __shared__ __align__(16) bf16 smem[20480];   // 40 KB
    bf16* Ks = smem;           // [2][64][64]
    bf16* Vt = smem + 8192;    // [2][64][64]  [hd][key]
    bf16* Ps = smem + 16384;   // [wave][16][64]; also Q staging (wave-local rows)
    bf16* Qs = Ps;

    const int tid = threadIdx.x, wave = tid >> 6, lane = tid & 63;
    const int quad = lane >> 4, l16 = lane & 15;
    const int gb = blockIdx.x;
    const int xcd = gb & 7, rr = gb >> 3;
    const int hi = rr >> 5, lo = rr & 31;
    const int t = (hi == 0) ? lo : (hi == 1) ? (31 - lo)
                : (hi == 2) ? (lo ^ 16) : (31 - (lo ^ 16));
    const int bh = xcd * 4 + hi;
    const int b = bh >> 4, h = bh & 15;
    const int q0 = t * 64;
    const size_t base = (size_t)(b * SS) * N_QKV;
    const bf16* Vg = Vt_g + (size_t)bh * 64 * SS;
    constexpr float C2 = 0.18033688011112042f;   // 0.125 * log2(e)
    const int l8r = lane >> 3, l8c = lane & 7;
    const int gch = (l8c ^ l8r) * 8;
    const int swz = l16 & 7;
    const int nkt = t + 1;

    {   // stage Q [64][64] swizzled into Ps region (wave-local 16 rows)
#pragma unroll
        for (int c = 0; c < 2; ++c) {
            int r0 = wave * 16 + c * 8;
            async16(QKV + base + (size_t)(q0 + r0 + l8r) * N_QKV + h * 64 + gch,
                    Qs + r0 * 64);
            // K/V tile 0 into buf 0
            async16(QKV + base + (size_t)(r0 + l8r) * N_QKV + DD + h * 64 + gch,
                    Ks + r0 * 64);
            async16(Vg + (size_t)(r0 + l8r) * SS + gch, Vt + r0 * 64);
        }
    }
    __syncthreads();   // vmcnt drained: Q + tile0 staged

    bf16x8 qf[2];
#pragma unroll
    for (int cc = 0; cc < 2; ++cc) {
        int row = wave * 16 + l16;
        qf[cc] = *(const bf16x8*)&Qs[row * 64 + ((cc * 4 + quad) ^ swz) * 8];
    }

    bf16x8 onesf = {};
    if (l16 == 0) {
#pragma unroll
        for (int e = 0; e < 8; ++e) onesf[e] = (bf16)1.0f;
    }

    floatx4 accv[4] = {};
    floatx4 acc5 = {};
    const int qg = q0 + wave * 16 + l16;

    for (int kt = 0; kt < nkt; ++kt) {
        const int buf = kt & 1;
        if (kt + 1 < nkt) {   // DMA next tile into buf^1; completes by end barrier
            const int k0n = (kt + 1) * 64;
            const int dst = (buf ^ 1) * 4096;
#pragma unroll
            for (int c = 0; c < 2; ++c) {
                int r0 = wave * 16 + c * 8;
                async16(QKV + base + (size_t)(k0n + r0 + l8r) * N_QKV + DD + h * 64 + gch,
                        Ks + dst + r0 * 64);
                async16(Vg + (size_t)(r0 + l8r) * SS + k0n + gch, Vt + dst + r0 * 64);
            }
        }
        const int k0 = kt * 64;

        // S^T tile: rows = keys, cols = q (l16)
        floatx4 st[4];
#pragma unroll
        for (int j = 0; j < 4; ++j) st[j] = (floatx4){};
        __builtin_amdgcn_s_setprio(1);
#pragma unroll
        for (int cc = 0; cc < 2; ++cc)
#pragma unroll
            for (int j = 0; j < 4; ++j) {
                bf16x8 kf = *(const bf16x8*)&Ks[buf * 4096 + (j * 16 + l16) * 64
                                                + ((cc * 4 + quad) ^ swz) * 8];
                st[j] = MFMA16(kf, qf[cc], st[j]);
            }
        __builtin_amdgcn_s_setprio(0);

        // causal mask: only the diagonal tile (kt == t)
        if (kt == nkt - 1) {
#pragma unroll
            for (int j = 0; j < 4; ++j) {
                int kb = k0 + j * 16 + quad * 4;
#pragma unroll
                for (int r = 0; r < 4; ++r)
                    if (kb + r > qg) st[j][r] = -__builtin_inff();
            }
        }

        // P = exp2(s*C2)  (fixed-max: no running max / rescale)
#pragma unroll
        for (int j = 0; j < 4; ++j) {
            bf16x4 pk4;
#pragma unroll
            for (int r = 0; r < 4; ++r)
                pk4[r] = (bf16)exp2c(st[j][r] * C2);
            *(bf16x4*)&Ps[wave * 1024 + l16 * 64
                          + ((2 * j + (quad >> 1)) ^ swz) * 8 + (quad & 1) * 4] = pk4;
        }

        // PV + denominator
        bf16x8 pf[2];
#pragma unroll
        for (int cc = 0; cc < 2; ++cc)
            pf[cc] = *(const bf16x8*)&Ps[wave * 1024 + l16 * 64
                                         + ((cc * 4 + quad) ^ swz) * 8];
        __builtin_amdgcn_s_setprio(1);
#pragma unroll
        for (int cc = 0; cc < 2; ++cc)
#pragma unroll
            for (int j = 0; j < 4; ++j) {
                bf16x8 vt = *(const bf16x8*)&Vt[buf * 4096 + (j * 16 + l16) * 64
                                                + ((cc * 4 + quad) ^ swz) * 8];
                accv[j] = MFMA16(pf[cc], vt, accv[j]);
            }
        acc5 = MFMA16(pf[0], onesf, acc5);
        acc5 = MFMA16(pf[1], onesf, acc5);
        __builtin_amdgcn_s_setprio(0);

        __syncthreads();   // readers done + next-tile DMA drained
    }

    // epilogue: denominators in acc5 col 0 (lanes l16==0)
    float inv[4];
#pragma unroll
    for (int r = 0; r < 4; ++r)
        inv[r] = 1.0f / __shfl(acc5[r], lane & 48, 64);
#pragma unroll
    for (int j = 0; j < 4; ++j)
#pragma unroll
        for (int r = 0; r < 4; ++r) {
            int row = b * SS + q0 + wave * 16 + quad * 4 + r;
            int col = h * 64 + j * 16 + l16;
            ctx[(size_t)row * DD + col] = (bf16)(accv[j][r] * inv[r]);
        }
}

extern "C" void kernel_launch(void* const* d_in, const int* in_sizes, int n_in,
                              void* d_out, int out_size, void* d_ws, size_t ws_size,
                              hipStream_t stream) {
    const float* x  = (const float*)d_in[0];
    const float* Wq = (const float*)d_in[1];
    const float* Wk = (const float*)d_in[2];
    const float* Wv = (const float*)d_in[3];
    const float* Wo = (const float*)d_in[4];
    const float* bo = (const float*)d_in[5];
    float* out = (float*)d_out;

    char* ws = (char*)d_ws;
    bf16* xb   = (bf16*)ws;                         //  8 MB
    bf16* WT   = (bf16*)(ws + (size_t)(8  << 20));  //  8 MB
    bf16* QKV  = (bf16*)(ws + (size_t)(16 << 20));  // 24 MB (V third unused)
    bf16* ctxb = (bf16*)(ws + (size_t)(40 << 20));  //  8 MB
    bf16* Vt_g = (bf16*)(ws + (size_t)(48 << 20));  //  8 MB

    prep_kernel<<<dim3(8192), dim3(256), 0, stream>>>(x, xb, Wq, Wk, Wv, Wo, WT);
    gemm192_kernel<<<dim3(N_QKV / 192, MM / 256), dim3(512), 0, stream>>>(
        xb, WT, QKV, Vt_g, DD, N_QKV);
    attn_kernel<<<dim3(1024), dim3(256), 0, stream>>>(QKV, Vt_g, ctxb);
    gemmo_kernel<<<dim3(DD / 128, MM / 128), dim3(512), 0, stream>>>(
        ctxb, WT + (size_t)3 * DD * DD, out, bo, DD, DD);
}

// Round 7
// 161.229 us; speedup vs baseline: 1.0186x; 1.0073x over previous
//
#include <hip/hip_runtime.h>

typedef __bf16 bf16;
typedef __attribute__((ext_vector_type(8))) __bf16 bf16x8;
typedef __attribute__((ext_vector_type(4))) __bf16 bf16x4;
typedef __attribute__((ext_vector_type(4))) float floatx4;

#define MFMA16(a, b, c) __builtin_amdgcn_mfma_f32_16x16x32_bf16((a), (b), (c), 0, 0, 0)

static constexpr int BB = 2, SS = 2048, DD = 1024, HH = 16;
static constexpr int MM = BB * SS;      // 4096
static constexpr int N_QKV = 3 * DD;    // 3072

__device__ __forceinline__ float exp2c(float x) {
#if __has_builtin(__builtin_amdgcn_exp2f)
    return __builtin_amdgcn_exp2f(x);
#else
    return exp2f(x);
#endif
}

// async 16B global->LDS (lane i of wave lands at ldsbase + i*16)
__device__ __forceinline__ void async16(const void* g, void* l) {
    __builtin_amdgcn_global_load_lds(
        (const __attribute__((address_space(1))) unsigned int*)g,
        (__attribute__((address_space(3))) unsigned int*)l, 16, 0, 0);
}

// ---------------- prep: x cast (blocks 0..4095) + W transpose (blocks 4096..8191) ----------------
__global__ __launch_bounds__(256) void prep_kernel(const float* __restrict__ x,
                                                   bf16* __restrict__ xb,
                                                   const float* __restrict__ w0,
                                                   const float* __restrict__ w1,
                                                   const float* __restrict__ w2,
                                                   const float* __restrict__ w3,
                                                   bf16* __restrict__ outT) {
    const int blk = blockIdx.x, tid = threadIdx.x;
    if (blk < 4096) {
        int i = blk * 1024 + tid * 4;
        float4 v = *(const float4*)(x + i);
        bf16x4 o;
        o[0] = (bf16)v.x; o[1] = (bf16)v.y; o[2] = (bf16)v.z; o[3] = (bf16)v.w;
        *(bf16x4*)(xb + i) = o;
    } else {
        __shared__ float tile[32][33];
        const int wblk = blk - 4096;
        const int z = wblk >> 10, rem = wblk & 1023;
        const int by = rem >> 5, bx = rem & 31;
        const float* src = (z == 0) ? w0 : (z == 1) ? w1 : (z == 2) ? w2 : w3;
        bf16* dst = outT + (size_t)z * DD * DD;
        const int y0 = by * 32, x0 = bx * 32;
        {
            const int tx = tid & 7, ty = tid >> 3;   // 8 x 32 threads, float4 each
            float4 v = *(const float4*)(src + (size_t)(y0 + ty) * DD + x0 + tx * 4);
            tile[ty][tx * 4 + 0] = v.x;
            tile[ty][tx * 4 + 1] = v.y;
            tile[ty][tx * 4 + 2] = v.z;
            tile[ty][tx * 4 + 3] = v.w;
        }
        __syncthreads();
        {
            const int tx = tid & 7, c = tid >> 3;    // output row x0+c, 4 cols per thread
            bf16x4 o;
            o[0] = (bf16)tile[tx * 4 + 0][c];
            o[1] = (bf16)tile[tx * 4 + 1][c];
            o[2] = (bf16)tile[tx * 4 + 2][c];
            o[3] = (bf16)tile[tx * 4 + 3][c];
            *(bf16x4*)(dst + (size_t)(x0 + c) * DD + y0 + tx * 4) = o;
        }
    }
}

#define VMW(N) asm volatile("s_waitcnt vmcnt(" #N ")" ::: "memory")
#define BARX __builtin_amdgcn_s_barrier()

// ---------------- 256x192 deep-pipelined GEMM (QKV projection) ----------------
// r3-verified structure + r5 3-phase prefetch (measured best). Do not touch (r4/r5:
// further pipeline refinement is neutral; this is the structure's ceiling).
__global__ __launch_bounds__(512, 2) void gemm192_kernel(const bf16* __restrict__ A,
                                                         const bf16* __restrict__ Bt,
                                                         bf16* __restrict__ C,
                                                         bf16* __restrict__ Vt_g,
                                                         int K, int ldc) {
    __shared__ __align__(16) bf16 As[2 * 256 * 64];   // 64 KB
    __shared__ __align__(16) bf16 Bs[2 * 192 * 64];   // 48 KB
    const int tid = threadIdx.x, wave = tid >> 6, lane = tid & 63;
    const int quad = lane >> 4, l16 = lane & 15;
    const int wm = wave >> 2, wn = wave & 3;          // 2 x 4 wave grid
    const int m0 = blockIdx.y * 256, n0 = blockIdx.x * 192;
    const int l8r = lane >> 3, l8c = lane & 7;
    const int gch = (l8c ^ l8r) * 8;
    const int nk = K >> 6;

    floatx4 acc[2][4][3] = {};    // [mh][m'][n']
    bf16x8 af[4][2], bn[3][2];

#define STAGE_A(H, KN, BUF)                                                       \
    {                                                                             \
        _Pragma("unroll") for (int c = 0; c < 2; ++c) {                           \
            int r0 = (H) * 128 + c * 64 + wave * 8;                               \
            async16(A + (size_t)(m0 + r0 + l8r) * K + (KN) + gch,                 \
                    &As[(BUF) * 16384 + r0 * 64]);                                \
        }                                                                         \
    }
#define STAGE_B(KN, BUF)                                                          \
    {                                                                             \
        _Pragma("unroll") for (int c = 0; c < 3; ++c) {                           \
            int r0 = wave * 24 + c * 8;                                           \
            async16(Bt + (size_t)(n0 + r0 + l8r) * K + (KN) + gch,                \
                    &Bs[(BUF) * 12288 + r0 * 64]);                                \
        }                                                                         \
    }
#define READ_A(MH, BUF)                                                           \
    {                                                                             \
        _Pragma("unroll") for (int m = 0; m < 4; ++m) {                           \
            int row = (MH) * 128 + wm * 64 + m * 16 + l16;                        \
            _Pragma("unroll") for (int kk = 0; kk < 2; ++kk)                      \
                af[m][kk] = *(const bf16x8*)&As[(BUF) * 16384 + row * 64 +        \
                                               (((kk * 4 + quad) ^ (row & 7)) * 8)]; \
        }                                                                         \
    }
#define READ_B(BUF)                                                               \
    {                                                                             \
        _Pragma("unroll") for (int n = 0; n < 3; ++n) {                           \
            int row = wn * 48 + n * 16 + l16;                                     \
            _Pragma("unroll") for (int kk = 0; kk < 2; ++kk)                      \
                bn[n][kk] = *(const bf16x8*)&Bs[(BUF) * 12288 + row * 64 +        \
                                               (((kk * 4 + quad) ^ (row & 7)) * 8)]; \
        }                                                                         \
    }
#define MMAC(MH)                                                                  \
    {                                                                             \
        __builtin_amdgcn_s_setprio(1);                                            \
        _Pragma("unroll") for (int m = 0; m < 4; ++m)                             \
            _Pragma("unroll") for (int n = 0; n < 3; ++n)                         \
                _Pragma("unroll") for (int kk = 0; kk < 2; ++kk)                  \
                    acc[MH][m][n] = MFMA16(af[m][kk], bn[n][kk], acc[MH][m][n]);  \
        __builtin_amdgcn_s_setprio(0);                                            \
    }

    // prologue (FIFO): A0_0, B_0, A1_0, A0_1, B_1  -> 12 outstanding
    STAGE_A(0, 0, 0);
    STAGE_B(0, 0);
    STAGE_A(1, 0, 0);
    STAGE_A(0, 64, 1);
    STAGE_B(64, 1);

    for (int kt = 0; kt < nk; ++kt) {
        const int buf = kt & 1;
        const int k1 = (kt + 1) << 6, k2 = (kt + 2) << 6;
        const bool last = (kt == nk - 1);

        // phase 0 (mh=0): needs A0+B of tile kt (issued 3 phases ago)
        if (!last) { VMW(7); } else { VMW(2); }
        BARX;
        READ_A(0, buf);
        READ_B(buf);
        if (kt + 1 < nk) STAGE_A(1, k1, buf ^ 1);   // rows 128-255 of buf^1
        MMAC(0);

        // phase 1 (mh=1): needs A1 of tile kt
        if (!last) { VMW(7); } else { VMW(0); }
        BARX;
        READ_A(1, buf);
        if (kt + 2 < nk) { STAGE_A(0, k2, buf); STAGE_B(k2, buf); }  // rows 0-127 of buf
        MMAC(1);
    }

#undef STAGE_A
#undef STAGE_B
#undef READ_A
#undef READ_B
#undef MMAC

    // epilogue: per-fragment routing across the QK|V boundary (col 2048, 16-aligned)
#pragma unroll
    for (int mh = 0; mh < 2; ++mh)
#pragma unroll
        for (int m = 0; m < 4; ++m)
#pragma unroll
            for (int n = 0; n < 3; ++n) {
                int grow = m0 + mh * 128 + wm * 64 + m * 16 + quad * 4;
                int gcol0 = n0 + wn * 48 + n * 16;
                if (gcol0 >= 2048) {
                    int bb = grow >> 11, s = grow & (SS - 1);
                    int vcol = gcol0 + l16 - 2048;
                    int hh = vcol >> 6, hd = vcol & 63;
                    bf16x4 pk;
#pragma unroll
                    for (int r = 0; r < 4; ++r) pk[r] = (bf16)acc[mh][m][n][r];
                    *(bf16x4*)&Vt_g[(((size_t)(bb * 16 + hh)) * 64 + hd) * SS + s] = pk;
                } else {
#pragma unroll
                    for (int r = 0; r < 4; ++r)
                        C[(size_t)(grow + r) * ldc + gcol0 + l16] = (bf16)acc[mh][m][n][r];
                }
            }
}

// ---------------- 128x128 deep-pipelined GEMM (output projection, fp32 + bias) ----------------
// r5 config (measured equal-best). Do not touch.
__global__ __launch_bounds__(512, 2) void gemmo_kernel(const bf16* __restrict__ A,
                                                       const bf16* __restrict__ Bt,
                                                       float* __restrict__ C,
                                                       const float* __restrict__ bias,
                                                       int K, int ldc) {
    __shared__ __align__(16) bf16 As[2 * 128 * 64];   // 32 KB
    __shared__ __align__(16) bf16 Bs[2 * 128 * 64];   // 32 KB
    const int tid = threadIdx.x, wave = tid >> 6, lane = tid & 63;
    const int quad = lane >> 4, l16 = lane & 15;
    const int wm = wave >> 2, wn = wave & 3;          // 2 x 4 wave grid
    const int m0 = blockIdx.y * 128, n0 = blockIdx.x * 128;
    const int l8r = lane >> 3, l8c = lane & 7;
    const int gch = (l8c ^ l8r) * 8;
    const int nk = K >> 6;

    floatx4 acc[2][2][2] = {};    // [mh][m'][n']
    bf16x8 af[2][2], bn[2][2];

#define STAGE_A(H, KN, BUF)                                                       \
    {                                                                             \
        int r0 = (H) * 64 + wave * 8;                                             \
        async16(A + (size_t)(m0 + r0 + l8r) * K + (KN) + gch,                     \
                &As[(BUF) * 8192 + r0 * 64]);                                     \
    }
#define STAGE_B(KN, BUF)                                                          \
    {                                                                             \
        _Pragma("unroll") for (int c = 0; c < 2; ++c) {                           \
            int r0 = wave * 16 + c * 8;                                           \
            async16(Bt + (size_t)(n0 + r0 + l8r) * K + (KN) + gch,                \
                    &Bs[(BUF) * 8192 + r0 * 64]);                                 \
        }                                                                         \
    }
#define READ_A(MH, BUF)                                                           \
    {                                                                             \
        _Pragma("unroll") for (int m = 0; m < 2; ++m) {                           \
            int row = (MH) * 64 + wm * 32 + m * 16 + l16;                         \
            _Pragma("unroll") for (int kk = 0; kk < 2; ++kk)                      \
                af[m][kk] = *(const bf16x8*)&As[(BUF) * 8192 + row * 64 +         \
                                               (((kk * 4 + quad) ^ (row & 7)) * 8)]; \
        }                                                                         \
    }
#define READ_B(BUF)                                                               \
    {                                                                             \
        _Pragma("unroll") for (int n = 0; n < 2; ++n) {                           \
            int row = wn * 32 + n * 16 + l16;                                     \
            _Pragma("unroll") for (int kk = 0; kk < 2; ++kk)                      \
                bn[n][kk] = *(const bf16x8*)&Bs[(BUF) * 8192 + row * 64 +         \
                                               (((kk * 4 + quad) ^ (row & 7)) * 8)]; \
        }                                                                         \
    }
#define MMAC(MH)                                                                  \
    {                                                                             \
        __builtin_amdgcn_s_setprio(1);                                            \
        _Pragma("unroll") for (int m = 0; m < 2; ++m)                             \
            _Pragma("unroll") for (int n = 0; n < 2; ++n)                         \
                _Pragma("unroll") for (int kk = 0; kk < 2; ++kk)                  \
                    acc[MH][m][n] = MFMA16(af[m][kk], bn[n][kk], acc[MH][m][n]);  \
        __builtin_amdgcn_s_setprio(0);                                            \
    }

    // prologue (FIFO): A0_0, B_0, A1_0, A0_1, B_1 -> 7 outstanding
    STAGE_A(0, 0, 0);
    STAGE_B(0, 0);
    STAGE_A(1, 0, 0);
    STAGE_A(0, 64, 1);
    STAGE_B(64, 1);

    for (int kt = 0; kt < nk; ++kt) {
        const int buf = kt & 1;
        const int k1 = (kt + 1) << 6, k2 = (kt + 2) << 6;
        const bool last = (kt == nk - 1);

        // phase 0 (mh=0): needs A0+B of tile kt
        if (!last) { VMW(4); } else { VMW(1); }
        BARX;
        READ_A(0, buf);
        READ_B(buf);
        if (kt + 1 < nk) STAGE_A(1, k1, buf ^ 1);
        MMAC(0);

        // phase 1 (mh=1): needs A1 of tile kt
        if (!last) { VMW(4); } else { VMW(0); }
        BARX;
        READ_A(1, buf);
        if (kt + 2 < nk) { STAGE_A(0, k2, buf); STAGE_B(k2, buf); }
        MMAC(1);
    }

#undef VMW
#undef BARX
#undef STAGE_A
#undef STAGE_B
#undef READ_A
#undef READ_B
#undef MMAC

#pragma unroll
    for (int mh = 0; mh < 2; ++mh)
#pragma unroll
        for (int m = 0; m < 2; ++m)
#pragma unroll
            for (int n = 0; n < 2; ++n)
#pragma unroll
                for (int r = 0; r < 4; ++r) {
                    int row = m0 + mh * 64 + wm * 32 + m * 16 + quad * 4 + r;
                    int col = n0 + wn * 32 + n * 16 + l16;
                    C[(size_t)row * ldc + col] = acc[mh][m][n][r] + bias[col];
                }
}

// ---------------- fused causal attention ----------------
// r6 (re-submitted after infra failure; never executed): critical-chain-isolating
// t-map. Grid = 1024 blocks = exactly 4/CU capacity, no refill -> makespan = the
// t=31 blocks' 32-iteration barrier-serialized chains. Old map put each 32-chain on
// a CU with {17,16}-length co-blocks (~17 of its 32 iterations contended). New map
// (each column of TMAP is a bijection on lo=0..31, so every (bh, q-tile) is covered
// exactly once -> bit-identical output):
//   lo=0..3: the four 32-chains isolated with co-blocks of length {1,2,3} only.
//   lo=4..31: LPT pairs {k,33-k} x 2, anti-correlated (worst pack {4,31,18,17}).
__global__ __launch_bounds__(256, 4) void attn_kernel(const bf16* __restrict__ QKV,
                                                      const bf16* __restrict__ Vt_g,
                                                      bf16* __restrict__ ctx) {
    __shared__ __align__(16) bf16 smem[20480];   // 40 KB
    bf16* Ks = smem;           // [2][64][64]
    bf16* Vt = smem + 8192;    // [2][64][64]  [hd][key]
    bf16* Ps = smem + 16384;   // [wave][16][64]; also Q staging (wave-local rows)
    bf16* Qs = Ps;

    static const unsigned char TMAP[4][32] = {
        {31, 0, 1, 2,  3, 4, 5, 6, 7, 8, 9,10,11,12,13,14,15,16,17,18,19,20,21,22,23,24,25,26,27,28,29,30},
        { 0,31, 2, 1, 30,29,28,27,26,25,24,23,22,21,20,19,18,17,16,15,14,13,12,11,10, 9, 8, 7, 6, 5, 4, 3},
        { 1, 2,31, 0, 17,18,19,20,21,22,23,24,25,26,27,28,29,30, 3, 4, 5, 6, 7, 8, 9,10,11,12,13,14,15,16},
        { 2, 1, 0,31, 16,15,14,13,12,11,10, 9, 8, 7, 6, 5, 4, 3, 30,29,28,27,26,25,24,23,22,21,20,19,18,17}};

    const int tid = threadIdx.x, wave = tid >> 6, lane = tid & 63;
    const int quad = lane >> 4, l16 = lane & 15;
    const int gb = blockIdx.x;
    const int xcd = gb & 7, rr = gb >> 3;
    const int hi = rr >> 5, lo = rr & 31;
    const int t = TMAP[hi][lo];
    const int bh = xcd * 4 + hi;
    const int b = bh >> 4, h = bh & 15;
    const int q0 = t * 64;
    const size_t base = (size_t)(b * SS) * N_QKV;
    const bf16* Vg = Vt_g + (size_t)bh * 64 * SS;
    constexpr float C2 = 0.18033688011112042f;   // 0.125 * log2(e)
    const int l8r = lane >> 3, l8c = lane & 7;
    const int gch = (l8c ^ l8r) * 8;
    const int swz = l16 & 7;
    const int nkt = t + 1;

    {   // stage Q [64][64] swizzled into Ps region (wave-local 16 rows)
#pragma unroll
        for (int c = 0; c < 2; ++c) {
            int r0 = wave * 16 + c * 8;
            async16(QKV + base + (size_t)(q0 + r0 + l8r) * N_QKV + h * 64 + gch,
                    Qs + r0 * 64);
            // K/V tile 0 into buf 0
            async16(QKV + base + (size_t)(r0 + l8r) * N_QKV + DD + h * 64 + gch,
                    Ks + r0 * 64);
            async16(Vg + (size_t)(r0 + l8r) * SS + gch, Vt + r0 * 64);
        }
    }
    __syncthreads();   // vmcnt drained: Q + tile0 staged

    bf16x8 qf[2];
#pragma unroll
    for (int cc = 0; cc < 2; ++cc) {
        int row = wave * 16 + l16;
        qf[cc] = *(const bf16x8*)&Qs[row * 64 + ((cc * 4 + quad) ^ swz) * 8];
    }

    bf16x8 onesf = {};
    if (l16 == 0) {
#pragma unroll
        for (int e = 0; e < 8; ++e) onesf[e] = (bf16)1.0f;
    }

    floatx4 accv[4] = {};
    floatx4 acc5 = {};
    const int qg = q0 + wave * 16 + l16;

    for (int kt = 0; kt < nkt; ++kt) {
        const int buf = kt & 1;
        if (kt + 1 < nkt) {   // DMA next tile into buf^1; completes by end barrier
            const int k0n = (kt + 1) * 64;
            const int dst = (buf ^ 1) * 4096;
#pragma unroll
            for (int c = 0; c < 2; ++c) {
                int r0 = wave * 16 + c * 8;
                async16(QKV + base + (size_t)(k0n + r0 + l8r) * N_QKV + DD + h * 64 + gch,
                        Ks + dst + r0 * 64);
                async16(Vg + (size_t)(r0 + l8r) * SS + k0n + gch, Vt + dst + r0 * 64);
            }
        }
        const int k0 = kt * 64;

        // S^T tile: rows = keys, cols = q (l16)
        floatx4 st[4];
#pragma unroll
        for (int j = 0; j < 4; ++j) st[j] = (floatx4){};
        __builtin_amdgcn_s_setprio(1);
#pragma unroll
        for (int cc = 0; cc < 2; ++cc)
#pragma unroll
            for (int j = 0; j < 4; ++j) {
                bf16x8 kf = *(const bf16x8*)&Ks[buf * 4096 + (j * 16 + l16) * 64
                                                + ((cc * 4 + quad) ^ swz) * 8];
                st[j] = MFMA16(kf, qf[cc], st[j]);
            }
        __builtin_amdgcn_s_setprio(0);

        // causal mask: only the diagonal tile (kt == t)
        if (kt == nkt - 1) {
#pragma unroll
            for (int j = 0; j < 4; ++j) {
                int kb = k0 + j * 16 + quad * 4;
#pragma unroll
                for (int r = 0; r < 4; ++r)
                    if (kb + r > qg) st[j][r] = -__builtin_inff();
            }
        }

        // P = exp2(s*C2)  (fixed-max: no running max / rescale)
#pragma unroll
        for (int j = 0; j < 4; ++j) {
            bf16x4 pk4;
#pragma unroll
            for (int r = 0; r < 4; ++r)
                pk4[r] = (bf16)exp2c(st[j][r] * C2);
            *(bf16x4*)&Ps[wave * 1024 + l16 * 64
                          + ((2 * j + (quad >> 1)) ^ swz) * 8 + (quad & 1) * 4] = pk4;
        }

        // PV + denominator
        bf16x8 pf[2];
#pragma unroll
        for (int cc = 0; cc < 2; ++cc)
            pf[cc] = *(const bf16x8*)&Ps[wave * 1024 + l16 * 64
                                         + ((cc * 4 + quad) ^ swz) * 8];
        __builtin_amdgcn_s_setprio(1);
#pragma unroll
        for (int cc = 0; cc < 2; ++cc)
#pragma unroll
            for (int j = 0; j < 4; ++j) {
                bf16x8 vt = *(const bf16x8*)&Vt[buf * 4096 + (j * 16 + l16) * 64
                                                + ((cc * 4 + quad) ^ swz) * 8];
                accv[j] = MFMA16(pf[cc], vt, accv[j]);
            }
        acc5 = MFMA16(pf[0], onesf, acc5);
        acc5 = MFMA16(pf[1], onesf, acc5);
        __builtin_amdgcn_s_setprio(0);

        __syncthreads();   // readers done + next-tile DMA drained
    }

    // epilogue: denominators in acc5 col 0 (lanes l16==0)
    float inv[4];
#pragma unroll
    for (int r = 0; r < 4; ++r)
        inv[r] = 1.0f / __shfl(acc5[r], lane & 48, 64);
#pragma unroll
    for (int j = 0; j < 4; ++j)
#pragma unroll
        for (int r = 0; r < 4; ++r) {
            int row = b * SS + q0 + wave * 16 + quad * 4 + r;
            int col = h * 64 + j * 16 + l16;
            ctx[(size_t)row * DD + col] = (bf16)(accv[j][r] * inv[r]);
        }
}

extern "C" void kernel_launch(void* const* d_in, const int* in_sizes, int n_in,
                              void* d_out, int out_size, void* d_ws, size_t ws_size,
                              hipStream_t stream) {
    const float* x  = (const float*)d_in[0];
    const float* Wq = (const float*)d_in[1];
    const float* Wk = (const float*)d_in[2];
    const float* Wv = (const float*)d_in[3];
    const float* Wo = (const float*)d_in[4];
    const float* bo = (const float*)d_in[5];
    float* out = (float*)d_out;

    char* ws = (char*)d_ws;
    bf16* xb   = (bf16*)ws;                         //  8 MB
    bf16* WT   = (bf16*)(ws + (size_t)(8  << 20));  //  8 MB
    bf16* QKV  = (bf16*)(ws + (size_t)(16 << 20));  // 24 MB (V third unused)
    bf16* ctxb = (bf16*)(ws + (size_t)(40 << 20));  //  8 MB
    bf16* Vt_g = (bf16*)(ws + (size_t)(48 << 20));  //  8 MB

    prep_kernel<<<dim3(8192), dim3(256), 0, stream>>>(x, xb, Wq, Wk, Wv, Wo, WT);
    gemm192_kernel<<<dim3(N_QKV / 192, MM / 256), dim3(512), 0, stream>>>(
        xb, WT, QKV, Vt_g, DD, N_QKV);
    attn_kernel<<<dim3(1024), dim3(256), 0, stream>>>(QKV, Vt_g, ctxb);
    gemmo_kernel<<<dim3(DD / 128, MM / 128), dim3(512), 0, stream>>>(
        ctxb, WT + (size_t)3 * DD * DD, out, bo, DD, DD);
}